// Round 1
// baseline (1518.683 us; speedup 1.0000x reference)
//
#include <hip/hip_runtime.h>
#include <math.h>

#define G_HEADS 64
#define NSEQ    4096
#define DDIM    64
#define MFEAT   256
#define NORMC   0.35355339059327373f   /* 64^-0.25 */
#define RATIO   0.0625f                /* 256^-0.5 */
#define EPSC    1e-4f

__device__ __forceinline__ unsigned enc_f(float f) {
    unsigned b = __float_as_uint(f);
    return (b & 0x80000000u) ? ~b : (b | 0x80000000u);
}
__device__ __forceinline__ float dec_f(unsigned u) {
    return (u & 0x80000000u) ? __uint_as_float(u & 0x7FFFFFFFu) : __uint_as_float(~u);
}

// ---------------- Kernel A: K-side pass ----------------
// Computes (per head, n-sliced into 8 blocks):
//   A[m][e]  += sum_n exp(dash_k[n][m] - diag_k[n]) * v[n][e]
//   As[m]    += sum_n exp(dash_k[n][m] - diag_k[n])
//   Sv[e]    += sum_n v[n][e]
//   mxk[g]    = max_{n,m} dash_k   (monotone-uint atomicMax)
template<int NSLICE>
__global__ __launch_bounds__(256, 2)
void kernA(const float* __restrict__ kk, const float* __restrict__ vv,
           const float* __restrict__ proj, float* __restrict__ Apart,
           float* __restrict__ Aspart, float* __restrict__ Svpart,
           unsigned* __restrict__ mxk)
{
    const int slice = blockIdx.x;   // 0..7
    const int g     = blockIdx.y;   // head
    const int t     = threadIdx.x;  // 0..255 == feature m
    const int lane  = t & 63;
    const int w     = t >> 6;

    __shared__ float kld[64 * DDIM];
    __shared__ float vld[64 * DDIM];
    __shared__ float diag[64];
    __shared__ float svred[4 * 64];
    __shared__ float wred[4];

    // proj row m -> registers
    float4 p4[16];
    const float4* pr = reinterpret_cast<const float4*>(proj + (size_t)t * DDIM);
#pragma unroll
    for (int i = 0; i < 16; i++) p4[i] = pr[i];

    float a[DDIM];
#pragma unroll
    for (int e = 0; e < DDIM; e++) a[e] = 0.f;
    float as_acc = 0.f;
    float sv_acc = 0.f;
    float mloc   = -1e30f;

    const int rows_per_block = NSEQ / 8;       // 512
    const int r_begin = slice * rows_per_block;

    float4* kld4 = reinterpret_cast<float4*>(kld);
    float4* vld4 = reinterpret_cast<float4*>(vld);

    for (int r0 = r_begin; r0 < r_begin + rows_per_block; r0 += 64) {
        const float4* kb = reinterpret_cast<const float4*>(kk + ((size_t)g * NSEQ + r0) * DDIM);
        const float4* vb = reinterpret_cast<const float4*>(vv + ((size_t)g * NSEQ + r0) * DDIM);
#pragma unroll
        for (int i = 0; i < 4; i++) {
            kld4[t + 256 * i] = kb[t + 256 * i];
            vld4[t + 256 * i] = vb[t + 256 * i];
        }
        __syncthreads();
        // diag for this tile: wave w handles rows w*16 .. w*16+15 (lane = column)
#pragma unroll
        for (int i = 0; i < 16; i++) {
            int rr = w * 16 + i;
            float x = kld[rr * DDIM + lane];
            float s = x * x;
#pragma unroll
            for (int off = 32; off > 0; off >>= 1) s += __shfl_xor(s, off);
            if (lane == 0) diag[rr] = 0.0625f * s;   // 0.5 * NORMC^2 * sumsq
        }
        __syncthreads();

        for (int r = 0; r < 64; r++) {
            const float4* krow = kld4 + r * 16;
            float4 acc4 = {0.f, 0.f, 0.f, 0.f};
#pragma unroll
            for (int i = 0; i < 16; i++) {
                float4 kv = krow[i];
                float4 pv = p4[i];
                acc4.x += kv.x * pv.x; acc4.y += kv.y * pv.y;
                acc4.z += kv.z * pv.z; acc4.w += kv.w * pv.w;
            }
            float dash = NORMC * ((acc4.x + acc4.y) + (acc4.z + acc4.w));
            mloc = fmaxf(mloc, dash);
            float t1 = __expf(dash - diag[r]);
            as_acc += t1;
            const float4* vrow = vld4 + r * 16;
#pragma unroll
            for (int i = 0; i < 16; i++) {
                float4 v4 = vrow[i];
                a[4 * i + 0] += t1 * v4.x; a[4 * i + 1] += t1 * v4.y;
                a[4 * i + 2] += t1 * v4.z; a[4 * i + 3] += t1 * v4.w;
            }
        }
        // Sv partial: thread (w,lane) sums rows rr == w (mod 4), element lane
#pragma unroll
        for (int i = 0; i < 16; i++) sv_acc += vld[(w + 4 * i) * DDIM + lane];
        __syncthreads();
    }

    // block-max of dash -> atomicMax
    float mm = mloc;
#pragma unroll
    for (int off = 32; off > 0; off >>= 1) mm = fmaxf(mm, __shfl_xor(mm, off));
    if (lane == 0) wred[w] = mm;
    svred[w * 64 + lane] = sv_acc;
    __syncthreads();
    if (t == 0) {
        float m4 = fmaxf(fmaxf(wred[0], wred[1]), fmaxf(wred[2], wred[3]));
        atomicMax(&mxk[g], enc_f(m4));
    }
    const int out_slice = (NSLICE == 1) ? 0 : slice;
    float* Adst = Apart + (((size_t)g * NSLICE + out_slice) * MFEAT + t) * DDIM;
    if (NSLICE == 1) {
#pragma unroll
        for (int e = 0; e < DDIM; e++) atomicAdd(&Adst[e], a[e]);
        atomicAdd(&Aspart[(size_t)g * MFEAT + t], as_acc);
    } else {
        float4* Ad4 = reinterpret_cast<float4*>(Adst);
#pragma unroll
        for (int i = 0; i < 16; i++) {
            float4 vq = {a[4 * i], a[4 * i + 1], a[4 * i + 2], a[4 * i + 3]};
            Ad4[i] = vq;
        }
        Aspart[((size_t)g * NSLICE + slice) * MFEAT + t] = as_acc;
    }
    if (t < 64) {
        float s = svred[t] + svred[64 + t] + svred[128 + t] + svred[192 + t];
        if (NSLICE == 1) atomicAdd(&Svpart[(size_t)g * 64 + t], s);
        else             Svpart[((size_t)g * NSLICE + slice) * 64 + t] = s;
    }
}

// ---------------- Kernel B: reduce partials, apply e^{-mx} and eps terms ----------------
__global__ __launch_bounds__(256)
void kernB(const float* __restrict__ Apart, const float* __restrict__ Aspart,
           const float* __restrict__ Svpart, const unsigned* __restrict__ mxk,
           float* __restrict__ ctx, float* __restrict__ ksum, int nslice)
{
    const int g = blockIdx.x;
    const int t = threadIdx.x;
    __shared__ float svh[64];
    float emx = __expf(-dec_f(mxk[g]));
    if (t < 64) {
        float s = 0.f;
        for (int sb = 0; sb < nslice; sb++) s += Svpart[((size_t)g * nslice + sb) * 64 + t];
        svh[t] = s;
    }
    float as_s = 0.f;
    for (int sb = 0; sb < nslice; sb++) as_s += Aspart[((size_t)g * nslice + sb) * MFEAT + t];
    ksum[(size_t)g * MFEAT + t] = RATIO * (emx * as_s + EPSC * (float)NSEQ);
    __syncthreads();
    for (int i = 0; i < 64; i++) {
        int idx = i * 256 + t;       // m*64 + e
        float s = 0.f;
        for (int sb = 0; sb < nslice; sb++)
            s += Apart[((size_t)g * nslice + sb) * (MFEAT * DDIM) + idx];
        ctx[(size_t)g * (MFEAT * DDIM) + idx] = RATIO * (emx * s + EPSC * svh[idx & 63]);
    }
}

// ---------------- Kernel C: Q-side pass + output ----------------
__global__ __launch_bounds__(256, 2)
void kernC(const float* __restrict__ qq, const float* __restrict__ proj,
           const float* __restrict__ ctx, const float* __restrict__ ksum,
           float* __restrict__ outp)
{
    const int slice = blockIdx.x;   // 0..15
    const int g     = blockIdx.y;
    const int t     = threadIdx.x;
    const int lane  = t & 63;
    const int w     = t >> 6;       // quarter j == wave

    __shared__ float qld[64 * DDIM];
    __shared__ float diag[64];
    __shared__ float qp_lds[256];
    __shared__ float wmaxs[4];
    __shared__ float wsums[4];
    __shared__ float opart[4 * 64];

    float4 p4[16];
    const float4* pr = reinterpret_cast<const float4*>(proj + (size_t)t * DDIM);
#pragma unroll
    for (int i = 0; i < 16; i++) p4[i] = pr[i];

    // ctx column e=lane for m-quarter w -> 64 registers (coalesced loads)
    float cc[64];
    {
        const float* cbase = ctx + ((size_t)g * MFEAT + w * 64) * DDIM + lane;
#pragma unroll
        for (int mm = 0; mm < 64; mm++) cc[mm] = cbase[mm * DDIM];
    }
    float kls = ksum[(size_t)g * MFEAT + t];

    float4* qld4 = reinterpret_cast<float4*>(qld);
    const int rows_per_block = NSEQ / 16;     // 256
    const int r_begin = slice * rows_per_block;

    for (int r0 = r_begin; r0 < r_begin + rows_per_block; r0 += 64) {
        const float4* qb = reinterpret_cast<const float4*>(qq + ((size_t)g * NSEQ + r0) * DDIM);
#pragma unroll
        for (int i = 0; i < 4; i++) qld4[t + 256 * i] = qb[t + 256 * i];
        __syncthreads();
#pragma unroll
        for (int i = 0; i < 16; i++) {
            int rr = w * 16 + i;
            float x = qld[rr * DDIM + lane];
            float s = x * x;
#pragma unroll
            for (int off = 32; off > 0; off >>= 1) s += __shfl_xor(s, off);
            if (lane == 0) diag[rr] = 0.0625f * s;
        }
        __syncthreads();

        for (int r = 0; r < 64; r++) {
            const float4* qrow = qld4 + r * 16;
            float4 acc4 = {0.f, 0.f, 0.f, 0.f};
#pragma unroll
            for (int i = 0; i < 16; i++) {
                float4 qv = qrow[i]; float4 pv = p4[i];
                acc4.x += qv.x * pv.x; acc4.y += qv.y * pv.y;
                acc4.z += qv.z * pv.z; acc4.w += qv.w * pv.w;
            }
            float dash = NORMC * ((acc4.x + acc4.y) + (acc4.z + acc4.w));
            // row max over all 256 features
            float mx = dash;
#pragma unroll
            for (int off = 32; off > 0; off >>= 1) mx = fmaxf(mx, __shfl_xor(mx, off));
            if (lane == 0) wmaxs[w] = mx;
            __syncthreads();
            float rmax = fmaxf(fmaxf(wmaxs[0], wmaxs[1]), fmaxf(wmaxs[2], wmaxs[3]));
            float qp = RATIO * (__expf(dash - diag[r] - rmax) + EPSC);
            float dp = qp * kls;
#pragma unroll
            for (int off = 32; off > 0; off >>= 1) dp += __shfl_xor(dp, off);
            if (lane == 0) wsums[w] = dp;
            qp_lds[t] = qp;
            __syncthreads();
            // out partial for (e=lane), m-quarter w
            const float4* qp4 = reinterpret_cast<const float4*>(qp_lds + w * 64);
            float accq = 0.f;
#pragma unroll
            for (int i = 0; i < 16; i++) {
                float4 qpv = qp4[i];
                accq += qpv.x * cc[4 * i] + qpv.y * cc[4 * i + 1]
                      + qpv.z * cc[4 * i + 2] + qpv.w * cc[4 * i + 3];
            }
            opart[w * 64 + lane] = accq;
            __syncthreads();
            if (t < 64) {
                float den = wsums[0] + wsums[1] + wsums[2] + wsums[3];
                float o = (opart[t] + opart[64 + t] + opart[128 + t] + opart[192 + t]) / den;
                outp[((size_t)g * NSEQ + r0 + r) * DDIM + t] = o;
            }
        }
        __syncthreads();   // protect qld before next staging
    }
}

extern "C" void kernel_launch(void* const* d_in, const int* in_sizes, int n_in,
                              void* d_out, int out_size, void* d_ws, size_t ws_size,
                              hipStream_t stream)
{
    const float* q    = (const float*)d_in[0];
    const float* k    = (const float*)d_in[1];
    const float* v    = (const float*)d_in[2];
    const float* proj = (const float*)d_in[3];
    float* outp = (float*)d_out;

    // workspace layout (floats): Apart | Aspart | Svpart | ctx | ksum | mxk(u32)
    size_t fl8 = (size_t)G_HEADS * 8 * MFEAT * DDIM + (size_t)G_HEADS * 8 * MFEAT +
                 (size_t)G_HEADS * 8 * 64 + (size_t)G_HEADS * MFEAT * DDIM +
                 (size_t)G_HEADS * MFEAT;
    size_t bytes8 = fl8 * 4 + G_HEADS * 4;
    int nslice = (ws_size >= bytes8) ? 8 : 1;

    float* Apart  = (float*)d_ws;
    float* Aspart = Apart  + (size_t)G_HEADS * nslice * MFEAT * DDIM;
    float* Svpart = Aspart + (size_t)G_HEADS * nslice * MFEAT;
    float* ctx    = Svpart + (size_t)G_HEADS * nslice * 64;
    float* ksum   = ctx    + (size_t)G_HEADS * MFEAT * DDIM;
    unsigned* mxk = (unsigned*)(ksum + (size_t)G_HEADS * MFEAT);
    size_t total_bytes = (size_t)((char*)(mxk + G_HEADS) - (char*)d_ws);

    hipMemsetAsync(d_ws, 0, total_bytes, stream);

    if (nslice == 8)
        kernA<8><<<dim3(8, G_HEADS), 256, 0, stream>>>(k, v, proj, Apart, Aspart, Svpart, mxk);
    else
        kernA<1><<<dim3(8, G_HEADS), 256, 0, stream>>>(k, v, proj, Apart, Aspart, Svpart, mxk);
    kernB<<<G_HEADS, 256, 0, stream>>>(Apart, Aspart, Svpart, mxk, ctx, ksum, nslice);
    kernC<<<dim3(16, G_HEADS), 256, 0, stream>>>(q, proj, ctx, ksum, outp);
}

// Round 2
// 343.820 us; speedup vs baseline: 4.4171x; 4.4171x over previous
//
#include <hip/hip_runtime.h>
#include <math.h>

#define NSEQ  4096
#define DDIM  64
#define MFEAT 256
#define GH    64
#define NORMC 0.35355339059327373f   /* 64^-0.25 */
#define EPSC  1e-4f

typedef __bf16 bf16x8 __attribute__((ext_vector_type(8)));
typedef unsigned short u16x8 __attribute__((ext_vector_type(8)));
typedef float f32x4 __attribute__((ext_vector_type(4)));

__device__ __forceinline__ unsigned enc_f(float f) {
    unsigned b = __float_as_uint(f);
    return (b & 0x80000000u) ? ~b : (b | 0x80000000u);
}
__device__ __forceinline__ float dec_f(unsigned u) {
    return (u & 0x80000000u) ? __uint_as_float(u & 0x7FFFFFFFu) : __uint_as_float(~u);
}
// split f into bf16 hi (low 16 bits of result) and bf16 lo (high 16 bits)
__device__ __forceinline__ unsigned packsplit(float f) {
    unsigned hb = __float_as_uint(f) & 0xffff0000u;
    float lo = f - __uint_as_float(hb);
    unsigned lb = __float_as_uint(lo) >> 16;
    return (hb >> 16) | (lb << 16);
}
__device__ __forceinline__ void unpack8(const unsigned* p, bf16x8& h, bf16x8& l) {
    u16x8 hh, ll;
#pragma unroll
    for (int j = 0; j < 8; j++) {
        hh[j] = (unsigned short)(p[j] & 0xffffu);
        ll[j] = (unsigned short)(p[j] >> 16);
    }
    h = __builtin_bit_cast(bf16x8, hh);
    l = __builtin_bit_cast(bf16x8, ll);
}
__device__ __forceinline__ f32x4 zero4() { f32x4 z = {0.f, 0.f, 0.f, 0.f}; return z; }
__device__ __forceinline__ f32x4 mfma3(bf16x8 ah, bf16x8 al, bf16x8 bh, bf16x8 bl, f32x4 c) {
    c = __builtin_amdgcn_mfma_f32_16x16x32_bf16(ah, bh, c, 0, 0, 0);
    c = __builtin_amdgcn_mfma_f32_16x16x32_bf16(ah, bl, c, 0, 0, 0);
    c = __builtin_amdgcn_mfma_f32_16x16x32_bf16(al, bh, c, 0, 0, 0);
    return c;
}

// ================= Kernel A: K-side =================
// Per (slice, head): dash_k = K·(NORMC·P)^T via MFMA; w = exp(dash-diag);
// ctx-partial[m][e] = sum_n w·V ; As[m] = sum_n w ; Sv[e] = sum_n V ; mxk = max dash.
template<int NSLICE>
__global__ __launch_bounds__(256, 2)
void kernA(const float* __restrict__ kk, const float* __restrict__ vv,
           const float* __restrict__ proj, float* __restrict__ Apart,
           float* __restrict__ Aspart, float* __restrict__ Svpart,
           unsigned* __restrict__ mxk)
{
    const int slice = blockIdx.x;     // 0..7
    const int g     = blockIdx.y;     // head
    const int t     = threadIdx.x;
    const int lane  = t & 63;
    const int wq    = t >> 6;         // wave id == m-quarter
    const int li    = lane & 15;
    const int lg    = lane >> 4;

    __shared__ unsigned Kl[32 * 65];
    __shared__ unsigned Vl[32 * 65];
    __shared__ unsigned Wl[4][32 * 65];
    __shared__ float diag[32];
    __shared__ float svred[256];
    __shared__ float mxred[4];

    // P fragments (NORMC folded), per-wave m-quarter
    bf16x8 pfh[4][2], pfl[4][2];
#pragma unroll
    for (int u = 0; u < 4; u++)
#pragma unroll
    for (int s = 0; s < 2; s++) {
        const float* pr = proj + (size_t)(wq * 64 + u * 16 + li) * DDIM + s * 32 + lg * 8;
        unsigned pk[8];
#pragma unroll
        for (int j = 0; j < 8; j++) pk[j] = packsplit(NORMC * pr[j]);
        unpack8(pk, pfh[u][s], pfl[u][s]);
    }

    f32x4 cacc[4][4];
#pragma unroll
    for (int u = 0; u < 4; u++)
#pragma unroll
    for (int e = 0; e < 4; e++) cacc[u][e] = zero4();
    float as_loc[4] = {0.f, 0.f, 0.f, 0.f};
    float sv_loc = 0.f;
    float mloc = -1e30f;

    const int stg_n = t >> 3;
    const int stg_d = (t & 7) * 8;
    const int r_begin = slice * (NSEQ / 8);

    for (int r0 = r_begin; r0 < r_begin + NSEQ / 8; r0 += 32) {
        { // stage K,V (raw f32 -> packed split bf16), diag from raw
            const float* kb = kk + ((size_t)g * NSEQ + r0 + stg_n) * DDIM + stg_d;
            float4 a0 = ((const float4*)kb)[0], a1 = ((const float4*)kb)[1];
            float sq = a0.x*a0.x + a0.y*a0.y + a0.z*a0.z + a0.w*a0.w
                     + a1.x*a1.x + a1.y*a1.y + a1.z*a1.z + a1.w*a1.w;
            sq += __shfl_xor(sq, 1); sq += __shfl_xor(sq, 2); sq += __shfl_xor(sq, 4);
            if ((t & 7) == 0) diag[stg_n] = 0.0625f * sq;   // 0.5*NORMC^2*sumsq
            unsigned* kd = &Kl[stg_n * 65 + stg_d];
            kd[0]=packsplit(a0.x); kd[1]=packsplit(a0.y); kd[2]=packsplit(a0.z); kd[3]=packsplit(a0.w);
            kd[4]=packsplit(a1.x); kd[5]=packsplit(a1.y); kd[6]=packsplit(a1.z); kd[7]=packsplit(a1.w);
            const float* vb = vv + ((size_t)g * NSEQ + r0 + stg_n) * DDIM + stg_d;
            float4 b0 = ((const float4*)vb)[0], b1 = ((const float4*)vb)[1];
            unsigned* vd = &Vl[stg_n * 65 + stg_d];
            vd[0]=packsplit(b0.x); vd[1]=packsplit(b0.y); vd[2]=packsplit(b0.z); vd[3]=packsplit(b0.w);
            vd[4]=packsplit(b1.x); vd[5]=packsplit(b1.y); vd[6]=packsplit(b1.z); vd[7]=packsplit(b1.w);
        }
        __syncthreads();
        // Sv: wave wq sums rows [8wq,8wq+8), e = lane
#pragma unroll
        for (int i = 0; i < 8; i++) {
            unsigned pv = Vl[(wq * 8 + i) * 65 + lane];
            sv_loc += __uint_as_float(pv << 16) + __uint_as_float(pv & 0xffff0000u);
        }
        // GEMM1: dash
        f32x4 dacc[2][4];
#pragma unroll
        for (int tt = 0; tt < 2; tt++)
#pragma unroll
        for (int u = 0; u < 4; u++) dacc[tt][u] = zero4();
#pragma unroll
        for (int tt = 0; tt < 2; tt++)
#pragma unroll
        for (int s = 0; s < 2; s++) {
            unsigned ak[8];
            const unsigned* kr = &Kl[(tt * 16 + li) * 65 + s * 32 + lg * 8];
#pragma unroll
            for (int j = 0; j < 8; j++) ak[j] = kr[j];
            bf16x8 ah, al; unpack8(ak, ah, al);
#pragma unroll
            for (int u = 0; u < 4; u++) dacc[tt][u] = mfma3(ah, al, pfh[u][s], pfl[u][s], dacc[tt][u]);
        }
        // exp, write W (wave-private, [n][m] stride 65), As, max
#pragma unroll
        for (int tt = 0; tt < 2; tt++)
#pragma unroll
        for (int u = 0; u < 4; u++)
#pragma unroll
        for (int r = 0; r < 4; r++) {
            float dash = dacc[tt][u][r];
            mloc = fmaxf(mloc, dash);
            float w = __expf(dash - diag[tt * 16 + lg * 4 + r]);
            as_loc[u] += w;
            Wl[wq][(tt * 16 + lg * 4 + r) * 65 + u * 16 + li] = packsplit(w);
        }
        // GEMM2: ctx += W^T(A: i=m,k=n) · V(B: c=e,k=n)
        bf16x8 vh[4], vl2[4];
#pragma unroll
        for (int u2 = 0; u2 < 4; u2++) {
            unsigned vx[8];
            const unsigned* vr = &Vl[(lg * 8) * 65 + u2 * 16 + li];
#pragma unroll
            for (int j = 0; j < 8; j++) vx[j] = vr[j * 65];
            unpack8(vx, vh[u2], vl2[u2]);
        }
#pragma unroll
        for (int u = 0; u < 4; u++) {
            unsigned aw[8];
            const unsigned* wr = &Wl[wq][(lg * 8) * 65 + u * 16 + li];
#pragma unroll
            for (int j = 0; j < 8; j++) aw[j] = wr[j * 65];
            bf16x8 wh, wl_; unpack8(aw, wh, wl_);
#pragma unroll
            for (int u2 = 0; u2 < 4; u2++) cacc[u][u2] = mfma3(wh, wl_, vh[u2], vl2[u2], cacc[u][u2]);
        }
        __syncthreads();
    }

    // reductions
    svred[t] = sv_loc;
    float mm = mloc;
#pragma unroll
    for (int off = 32; off >= 1; off >>= 1) mm = fmaxf(mm, __shfl_xor(mm, off));
    if (lane == 0) mxred[wq] = mm;
#pragma unroll
    for (int u = 0; u < 4; u++) {
        float a = as_loc[u];
        a += __shfl_xor(a, 16); a += __shfl_xor(a, 32);
        as_loc[u] = a;
    }
    __syncthreads();
    if (t == 0) {
        float m4 = fmaxf(fmaxf(mxred[0], mxred[1]), fmaxf(mxred[2], mxred[3]));
        atomicMax(mxk + g, enc_f(m4));
    }
    if (t < 64) {
        float s = svred[t] + svred[64 + t] + svred[128 + t] + svred[192 + t];
        if (NSLICE == 8) Svpart[((size_t)g * 8 + slice) * 64 + t] = s;
        else             atomicAdd(&Svpart[(size_t)g * 64 + t], s);
    }
    if (lane < 16) {
#pragma unroll
        for (int u = 0; u < 4; u++) {
            int m = wq * 64 + u * 16 + lane;
            if (NSLICE == 8) Aspart[((size_t)g * 8 + slice) * 256 + m] = as_loc[u];
            else             atomicAdd(&Aspart[(size_t)g * 256 + m], as_loc[u]);
        }
    }
    if (NSLICE == 8) {
        float* Ad = Apart + ((size_t)g * 8 + slice) * (256 * 64);
#pragma unroll
        for (int u = 0; u < 4; u++)
#pragma unroll
        for (int u2 = 0; u2 < 4; u2++)
#pragma unroll
        for (int r = 0; r < 4; r++)
            Ad[(wq * 64 + u * 16 + lg * 4 + r) * 64 + u2 * 16 + li] = cacc[u][u2][r];
    } else {
        float* Ad = Apart + (size_t)g * (256 * 64);
#pragma unroll
        for (int u = 0; u < 4; u++)
#pragma unroll
        for (int u2 = 0; u2 < 4; u2++)
#pragma unroll
        for (int r = 0; r < 4; r++)
            atomicAdd(&Ad[(wq * 64 + u * 16 + lg * 4 + r) * 64 + u2 * 16 + li], cacc[u][u2][r]);
    }
}

// ================= Kernel B: reduce partials =================
__global__ __launch_bounds__(256)
void kernB(const float* __restrict__ Apart, const float* __restrict__ Aspart,
           const float* __restrict__ Svpart, const unsigned* __restrict__ mxk,
           float* __restrict__ ctx, float* __restrict__ ksum, int nslice)
{
    const int g = blockIdx.x;
    const int t = threadIdx.x;
    __shared__ float svh[64];
    float emx = __expf(-dec_f(mxk[g]));
    if (t < 64) {
        float s = 0.f;
        for (int sb = 0; sb < nslice; sb++) s += Svpart[((size_t)g * nslice + sb) * 64 + t];
        svh[t] = s;
    }
    float as_s = 0.f;
    for (int sb = 0; sb < nslice; sb++) as_s += Aspart[((size_t)g * nslice + sb) * 256 + t];
    ksum[(size_t)g * 256 + t] = emx * as_s + EPSC * (float)NSEQ;
    __syncthreads();
    for (int i = 0; i < 64; i++) {
        int idx = i * 256 + t;   // m*64 + e
        float s = 0.f;
        for (int sb = 0; sb < nslice; sb++)
            s += Apart[((size_t)g * nslice + sb) * (256 * 64) + idx];
        ctx[(size_t)g * (256 * 64) + idx] = emx * s + EPSC * svh[idx & 63];
    }
}

// ================= Kernel C: Q-side + output =================
__global__ __launch_bounds__(256, 2)
void kernC(const float* __restrict__ qq, const float* __restrict__ proj,
           const float* __restrict__ ctx, const float* __restrict__ ksum,
           float* __restrict__ outp)
{
    const int slice = blockIdx.x;   // 0..15
    const int g     = blockIdx.y;
    const int t     = threadIdx.x;
    const int lane  = t & 63;
    const int wq    = t >> 6;
    const int li    = lane & 15;
    const int lg    = lane >> 4;

    __shared__ unsigned Ql[32 * 65];
    __shared__ unsigned QPl[4][32 * 65];   // qp packed; later reused as f32 out partials
    __shared__ float diag[32];
    __shared__ float rmax4[4][32];
    __shared__ float comb[32];
    __shared__ float denp[4][32];
    __shared__ float denc[32];

    bf16x8 pfh[4][2], pfl[4][2];
#pragma unroll
    for (int u = 0; u < 4; u++)
#pragma unroll
    for (int s = 0; s < 2; s++) {
        const float* pr = proj + (size_t)(wq * 64 + u * 16 + li) * DDIM + s * 32 + lg * 8;
        unsigned pk[8];
#pragma unroll
        for (int j = 0; j < 8; j++) pk[j] = packsplit(NORMC * pr[j]);
        unpack8(pk, pfh[u][s], pfl[u][s]);
    }
    // ctx fragments for this wave's m-quarter: B(c=e, k=m-local)
    bf16x8 cfh[4][2], cfl[4][2];
#pragma unroll
    for (int u2 = 0; u2 < 4; u2++)
#pragma unroll
    for (int s = 0; s < 2; s++) {
        unsigned ck[8];
#pragma unroll
        for (int j = 0; j < 8; j++)
            ck[j] = packsplit(ctx[((size_t)g * 256 + wq * 64 + s * 32 + lg * 8 + j) * 64 + u2 * 16 + li]);
        unpack8(ck, cfh[u2][s], cfl[u2][s]);
    }
    float ksm[4];
#pragma unroll
    for (int u = 0; u < 4; u++) ksm[u] = ksum[(size_t)g * 256 + wq * 64 + u * 16 + li];

    const int stg_n = t >> 3;
    const int stg_d = (t & 7) * 8;
    const int r_begin = slice * (NSEQ / 16);

    for (int r0 = r_begin; r0 < r_begin + NSEQ / 16; r0 += 32) {
        { // stage Q
            const float* qb = qq + ((size_t)g * NSEQ + r0 + stg_n) * DDIM + stg_d;
            float4 a0 = ((const float4*)qb)[0], a1 = ((const float4*)qb)[1];
            float sq = a0.x*a0.x + a0.y*a0.y + a0.z*a0.z + a0.w*a0.w
                     + a1.x*a1.x + a1.y*a1.y + a1.z*a1.z + a1.w*a1.w;
            sq += __shfl_xor(sq, 1); sq += __shfl_xor(sq, 2); sq += __shfl_xor(sq, 4);
            if ((t & 7) == 0) diag[stg_n] = 0.0625f * sq;
            unsigned* qd = &Ql[stg_n * 65 + stg_d];
            qd[0]=packsplit(a0.x); qd[1]=packsplit(a0.y); qd[2]=packsplit(a0.z); qd[3]=packsplit(a0.w);
            qd[4]=packsplit(a1.x); qd[5]=packsplit(a1.y); qd[6]=packsplit(a1.z); qd[7]=packsplit(a1.w);
        }
        __syncthreads();
        // GEMM1: dash_q
        f32x4 dacc[2][4];
#pragma unroll
        for (int tt = 0; tt < 2; tt++)
#pragma unroll
        for (int u = 0; u < 4; u++) dacc[tt][u] = zero4();
#pragma unroll
        for (int tt = 0; tt < 2; tt++)
#pragma unroll
        for (int s = 0; s < 2; s++) {
            unsigned ak[8];
            const unsigned* qr = &Ql[(tt * 16 + li) * 65 + s * 32 + lg * 8];
#pragma unroll
            for (int j = 0; j < 8; j++) ak[j] = qr[j];
            bf16x8 ah, al; unpack8(ak, ah, al);
#pragma unroll
            for (int u = 0; u < 4; u++) dacc[tt][u] = mfma3(ah, al, pfh[u][s], pfl[u][s], dacc[tt][u]);
        }
        // row max over m
#pragma unroll
        for (int tt = 0; tt < 2; tt++)
#pragma unroll
        for (int r = 0; r < 4; r++) {
            float v = fmaxf(fmaxf(dacc[tt][0][r], dacc[tt][1][r]),
                            fmaxf(dacc[tt][2][r], dacc[tt][3][r]));
            v = fmaxf(v, __shfl_xor(v, 1));
            v = fmaxf(v, __shfl_xor(v, 2));
            v = fmaxf(v, __shfl_xor(v, 4));
            v = fmaxf(v, __shfl_xor(v, 8));
            if (li == 0) rmax4[wq][tt * 16 + lg * 4 + r] = v;
        }
        __syncthreads();
        if (t < 32) comb[t] = diag[t] + fmaxf(fmaxf(rmax4[0][t], rmax4[1][t]),
                                              fmaxf(rmax4[2][t], rmax4[3][t]));
        __syncthreads();
        // qp, den partial, QP write ([n][m-local] stride 65, wave-private)
        float dl[2][4] = {{0.f,0.f,0.f,0.f},{0.f,0.f,0.f,0.f}};
#pragma unroll
        for (int tt = 0; tt < 2; tt++) {
            float cb[4];
#pragma unroll
            for (int r = 0; r < 4; r++) cb[r] = comb[tt * 16 + lg * 4 + r];
#pragma unroll
            for (int u = 0; u < 4; u++)
#pragma unroll
            for (int r = 0; r < 4; r++) {
                float qp = __expf(dacc[tt][u][r] - cb[r]) + EPSC;
                dl[tt][r] += qp * ksm[u];
                QPl[wq][(tt * 16 + lg * 4 + r) * 65 + u * 16 + li] = packsplit(qp);
            }
        }
#pragma unroll
        for (int tt = 0; tt < 2; tt++)
#pragma unroll
        for (int r = 0; r < 4; r++) {
            float v = dl[tt][r];
            v += __shfl_xor(v, 1); v += __shfl_xor(v, 2);
            v += __shfl_xor(v, 4); v += __shfl_xor(v, 8);
            if (li == 0) denp[wq][tt * 16 + lg * 4 + r] = v;
        }
        __syncthreads();
        if (t < 32) denc[t] = denp[0][t] + denp[1][t] + denp[2][t] + denp[3][t];
        // GEMM3: out-partial (A: i=n, k=m-local from QPl; B: ctx frags)
        f32x4 oacc[2][4];
#pragma unroll
        for (int tt = 0; tt < 2; tt++)
#pragma unroll
        for (int u2 = 0; u2 < 4; u2++) oacc[tt][u2] = zero4();
#pragma unroll
        for (int s = 0; s < 2; s++)
#pragma unroll
        for (int tt = 0; tt < 2; tt++) {
            unsigned aq[8];
            const unsigned* qr = &QPl[wq][(tt * 16 + li) * 65 + s * 32 + lg * 8];
#pragma unroll
            for (int j = 0; j < 8; j++) aq[j] = qr[j];
            bf16x8 ah, al; unpack8(aq, ah, al);
#pragma unroll
            for (int u2 = 0; u2 < 4; u2++)
                oacc[tt][u2] = mfma3(ah, al, cfh[u2][s], cfl[u2][s], oacc[tt][u2]);
        }
        // write out partials (reuse QPl[wq] as float buffer; own-wave reads are done)
        {
            float* ob = (float*)&QPl[wq][0];
#pragma unroll
            for (int tt = 0; tt < 2; tt++)
#pragma unroll
            for (int u2 = 0; u2 < 4; u2++)
#pragma unroll
            for (int r = 0; r < 4; r++)
                ob[(tt * 16 + lg * 4 + r) * 65 + u2 * 16 + li] = oacc[tt][u2][r];
        }
        __syncthreads();
        { // combine 4 wave partials, divide by den, write out
            int n = t >> 3, eb = (t & 7) * 8;
            float dinv = 1.0f / denc[n];
            float o[8];
#pragma unroll
            for (int j = 0; j < 8; j++) {
                float s = 0.f;
#pragma unroll
                for (int w4 = 0; w4 < 4; w4++)
                    s += ((const float*)&QPl[w4][0])[n * 65 + eb + j];
                o[j] = s * dinv;
            }
            float4 o0 = {o[0], o[1], o[2], o[3]};
            float4 o1 = {o[4], o[5], o[6], o[7]};
            float* op = outp + ((size_t)g * NSEQ + r0 + n) * DDIM + eb;
            ((float4*)op)[0] = o0;
            ((float4*)op)[1] = o1;
        }
        __syncthreads();
    }
}

extern "C" void kernel_launch(void* const* d_in, const int* in_sizes, int n_in,
                              void* d_out, int out_size, void* d_ws, size_t ws_size,
                              hipStream_t stream)
{
    const float* q    = (const float*)d_in[0];
    const float* k    = (const float*)d_in[1];
    const float* v    = (const float*)d_in[2];
    const float* proj = (const float*)d_in[3];
    float* outp = (float*)d_out;

    // ws layout: mxk(256B) | Apart | Aspart | Svpart | ctx | ksum
    size_t need8 = 256 + 4ull * ((size_t)GH*8*256*64 + (size_t)GH*8*256 + (size_t)GH*8*64 +
                                 (size_t)GH*256*64 + (size_t)GH*256);
    int ns = (ws_size >= need8) ? 8 : 1;

    unsigned* mxk = (unsigned*)d_ws;
    float* Apart  = (float*)((char*)d_ws + 256);
    float* Aspart = Apart  + (size_t)GH * ns * 256 * 64;
    float* Svpart = Aspart + (size_t)GH * ns * 256;
    float* ctx    = Svpart + (size_t)GH * ns * 64;
    float* ksum   = ctx    + (size_t)GH * 256 * 64;

    if (ns == 8) {
        hipMemsetAsync(d_ws, 0, 256, stream);
        kernA<8><<<dim3(8, GH), 256, 0, stream>>>(k, v, proj, Apart, Aspart, Svpart, mxk);
    } else {
        size_t zb = 256 + 4ull * ((size_t)GH*256*64 + (size_t)GH*256 + (size_t)GH*64);
        hipMemsetAsync(d_ws, 0, zb, stream);
        kernA<1><<<dim3(8, GH), 256, 0, stream>>>(k, v, proj, Apart, Aspart, Svpart, mxk);
    }
    kernB<<<GH, 256, 0, stream>>>(Apart, Aspart, Svpart, mxk, ctx, ksum, ns);
    kernC<<<dim3(16, GH), 256, 0, stream>>>(q, proj, ctx, ksum, outp);
}

// Round 3
// 222.743 us; speedup vs baseline: 6.8181x; 1.5436x over previous
//
#include <hip/hip_runtime.h>
#include <math.h>

#define NSEQ  4096
#define DDIM  64
#define GH    64
#define NORMC 0.35355339059327373f   /* 64^-0.25 */
#define EPSC  1e-4f

typedef __bf16 bf16x8 __attribute__((ext_vector_type(8)));
typedef unsigned short u16x8 __attribute__((ext_vector_type(8)));
typedef float f32x4 __attribute__((ext_vector_type(4)));

__device__ __forceinline__ unsigned enc_f(float f) {
    unsigned b = __float_as_uint(f);
    return (b & 0x80000000u) ? ~b : (b | 0x80000000u);
}
__device__ __forceinline__ float dec_f(unsigned u) {
    return (u & 0x80000000u) ? __uint_as_float(u & 0x7FFFFFFFu) : __uint_as_float(~u);
}
// split f into bf16 hi and bf16 lo (residual)
__device__ __forceinline__ void split_hl(float f, unsigned short& h, unsigned short& l) {
    unsigned u = __float_as_uint(f);
    unsigned hb = u & 0xffff0000u;
    h = (unsigned short)(hb >> 16);
    l = (unsigned short)(__float_as_uint(f - __uint_as_float(hb)) >> 16);
}
__device__ __forceinline__ unsigned packsplit(float f) {
    unsigned short h, l;
    split_hl(f, h, l);
    return (unsigned)h | ((unsigned)l << 16);
}
__device__ __forceinline__ void unpack8(const unsigned* p, bf16x8& h, bf16x8& l) {
    u16x8 hh, ll;
#pragma unroll
    for (int j = 0; j < 8; j++) {
        hh[j] = (unsigned short)(p[j] & 0xffffu);
        ll[j] = (unsigned short)(p[j] >> 16);
    }
    h = __builtin_bit_cast(bf16x8, hh);
    l = __builtin_bit_cast(bf16x8, ll);
}
__device__ __forceinline__ bf16x8 ldfrag(const unsigned short* p) {
    return __builtin_bit_cast(bf16x8, *(const u16x8*)p);
}
__device__ __forceinline__ f32x4 zero4() { f32x4 z = {0.f, 0.f, 0.f, 0.f}; return z; }
__device__ __forceinline__ f32x4 mfma3(bf16x8 ah, bf16x8 al, bf16x8 bh, bf16x8 bl, f32x4 c) {
    c = __builtin_amdgcn_mfma_f32_16x16x32_bf16(ah, bh, c, 0, 0, 0);
    c = __builtin_amdgcn_mfma_f32_16x16x32_bf16(ah, bl, c, 0, 0, 0);
    c = __builtin_amdgcn_mfma_f32_16x16x32_bf16(al, bh, c, 0, 0, 0);
    return c;
}

// ================= Kernel A: K-side =================
template<int NSLICE>
__global__ __launch_bounds__(256, 2)
void kernA(const float* __restrict__ kk, const float* __restrict__ vv,
           const float* __restrict__ proj, float* __restrict__ Apart,
           float* __restrict__ Aspart, float* __restrict__ Svpart,
           unsigned* __restrict__ mxk)
{
    const int slices = (NSLICE == 1) ? 8 : NSLICE;
    const int slice = blockIdx.x;
    const int g     = blockIdx.y;
    const int t     = threadIdx.x;
    const int lane  = t & 63;
    const int wq    = t >> 6;
    const int li    = lane & 15;
    const int lg    = lane >> 4;

    __shared__ __align__(16) unsigned short Khi[2048];
    __shared__ __align__(16) unsigned short Klo[2048];
    __shared__ unsigned Vl[32 * 66];
    __shared__ unsigned Wl[4][32 * 66];
    __shared__ float diag[32];
    __shared__ float svred[4][64];
    __shared__ float mxred[4];

    // P fragments (NORMC folded)
    bf16x8 pfh[4][2], pfl[4][2];
#pragma unroll
    for (int u = 0; u < 4; u++)
#pragma unroll
    for (int s = 0; s < 2; s++) {
        const float* pr = proj + (size_t)(wq * 64 + u * 16 + li) * DDIM + s * 32 + lg * 8;
        u16x8 hh, ll;
#pragma unroll
        for (int j = 0; j < 8; j++) {
            unsigned short h, l;
            split_hl(NORMC * pr[j], h, l);
            hh[j] = h; ll[j] = l;
        }
        pfh[u][s] = __builtin_bit_cast(bf16x8, hh);
        pfl[u][s] = __builtin_bit_cast(bf16x8, ll);
    }

    f32x4 cacc[4][4];
#pragma unroll
    for (int u = 0; u < 4; u++)
#pragma unroll
    for (int e = 0; e < 4; e++) cacc[u][e] = zero4();
    float as_loc[4] = {0.f, 0.f, 0.f, 0.f};
    float sv8[8] = {0.f,0.f,0.f,0.f,0.f,0.f,0.f,0.f};
    float mloc = -1e30f;

    const int stg_n = t >> 3;
    const int stg_c = t & 7;
    const int rows_per = NSEQ / slices;
    const int r_begin = slice * rows_per;

    for (int r0 = r_begin; r0 < r_begin + rows_per; r0 += 32) {
        { // stage K (hi/lo planes, XOR-swizzled) + diag ; V packed stride 66 + Sv regs
            const float4* kb = (const float4*)(kk + ((size_t)g * NSEQ + r0 + stg_n) * DDIM + stg_c * 8);
            float4 a0 = kb[0], a1 = kb[1];
            float sq = a0.x*a0.x + a0.y*a0.y + a0.z*a0.z + a0.w*a0.w
                     + a1.x*a1.x + a1.y*a1.y + a1.z*a1.z + a1.w*a1.w;
            sq += __shfl_xor(sq, 1); sq += __shfl_xor(sq, 2); sq += __shfl_xor(sq, 4);
            if (stg_c == 0) diag[stg_n] = 0.0625f * sq;
            u16x8 h8, l8;
            {
                unsigned short h, l;
                split_hl(a0.x,h,l); h8[0]=h; l8[0]=l;
                split_hl(a0.y,h,l); h8[1]=h; l8[1]=l;
                split_hl(a0.z,h,l); h8[2]=h; l8[2]=l;
                split_hl(a0.w,h,l); h8[3]=h; l8[3]=l;
                split_hl(a1.x,h,l); h8[4]=h; l8[4]=l;
                split_hl(a1.y,h,l); h8[5]=h; l8[5]=l;
                split_hl(a1.z,h,l); h8[6]=h; l8[6]=l;
                split_hl(a1.w,h,l); h8[7]=h; l8[7]=l;
            }
            int idx = stg_n * 64 + (stg_c ^ (stg_n & 7)) * 8;
            *(u16x8*)&Khi[idx] = h8;
            *(u16x8*)&Klo[idx] = l8;
            const float4* vb = (const float4*)(vv + ((size_t)g * NSEQ + r0 + stg_n) * DDIM + stg_c * 8);
            float4 b0 = vb[0], b1 = vb[1];
            sv8[0]+=b0.x; sv8[1]+=b0.y; sv8[2]+=b0.z; sv8[3]+=b0.w;
            sv8[4]+=b1.x; sv8[5]+=b1.y; sv8[6]+=b1.z; sv8[7]+=b1.w;
            unsigned* vd = &Vl[stg_n * 66 + stg_c * 8];
            vd[0]=packsplit(b0.x); vd[1]=packsplit(b0.y); vd[2]=packsplit(b0.z); vd[3]=packsplit(b0.w);
            vd[4]=packsplit(b1.x); vd[5]=packsplit(b1.y); vd[6]=packsplit(b1.z); vd[7]=packsplit(b1.w);
        }
        __syncthreads();
        // GEMM1: dash = K · P^T
        f32x4 dacc[2][4];
#pragma unroll
        for (int tt = 0; tt < 2; tt++)
#pragma unroll
        for (int u = 0; u < 4; u++) dacc[tt][u] = zero4();
#pragma unroll
        for (int tt = 0; tt < 2; tt++)
#pragma unroll
        for (int s = 0; s < 2; s++) {
            int idx = (tt * 16 + li) * 64 + ((s * 4 + lg) ^ (li & 7)) * 8;
            bf16x8 ah = ldfrag(&Khi[idx]);
            bf16x8 al = ldfrag(&Klo[idx]);
#pragma unroll
            for (int u = 0; u < 4; u++) dacc[tt][u] = mfma3(ah, al, pfh[u][s], pfl[u][s], dacc[tt][u]);
        }
        // exp -> W (wave-private [n][m] stride 66)
#pragma unroll
        for (int tt = 0; tt < 2; tt++)
#pragma unroll
        for (int u = 0; u < 4; u++)
#pragma unroll
        for (int r = 0; r < 4; r++) {
            float dash = dacc[tt][u][r];
            mloc = fmaxf(mloc, dash);
            float w = __expf(dash - diag[tt * 16 + lg * 4 + r]);
            as_loc[u] += w;
            Wl[wq][(tt * 16 + lg * 4 + r) * 66 + u * 16 + li] = packsplit(w);
        }
        // GEMM2: ctx += W^T · V
        bf16x8 vh[4], vl2[4];
#pragma unroll
        for (int u2 = 0; u2 < 4; u2++) {
            unsigned vx[8];
            const unsigned* vr = &Vl[(lg * 8) * 66 + u2 * 16 + li];
#pragma unroll
            for (int j = 0; j < 8; j++) vx[j] = vr[j * 66];
            unpack8(vx, vh[u2], vl2[u2]);
        }
#pragma unroll
        for (int u = 0; u < 4; u++) {
            unsigned aw[8];
            const unsigned* wr = &Wl[wq][(lg * 8) * 66 + u * 16 + li];
#pragma unroll
            for (int j = 0; j < 8; j++) aw[j] = wr[j * 66];
            bf16x8 wh, wl_;
            unpack8(aw, wh, wl_);
#pragma unroll
            for (int u2 = 0; u2 < 4; u2++) cacc[u][u2] = mfma3(wh, wl_, vh[u2], vl2[u2], cacc[u][u2]);
        }
        __syncthreads();
    }

    // epilogue reductions
#pragma unroll
    for (int j = 0; j < 8; j++) {
        float s = sv8[j];
        s += __shfl_xor(s, 8); s += __shfl_xor(s, 16); s += __shfl_xor(s, 32);
        sv8[j] = s;
    }
    if (lane < 8) {
#pragma unroll
        for (int j = 0; j < 8; j++) svred[wq][lane * 8 + j] = sv8[j];
    }
    float mm = mloc;
#pragma unroll
    for (int off = 32; off >= 1; off >>= 1) mm = fmaxf(mm, __shfl_xor(mm, off));
    if (lane == 0) mxred[wq] = mm;
#pragma unroll
    for (int u = 0; u < 4; u++) {
        float a = as_loc[u];
        a += __shfl_xor(a, 16); a += __shfl_xor(a, 32);
        as_loc[u] = a;
    }
    __syncthreads();
    if (t == 0) {
        float m4 = fmaxf(fmaxf(mxred[0], mxred[1]), fmaxf(mxred[2], mxred[3]));
        atomicMax(mxk + g, enc_f(m4));
    }
    if (t < 64) {
        float s = svred[0][t] + svred[1][t] + svred[2][t] + svred[3][t];
        if (NSLICE == 1) atomicAdd(&Svpart[(size_t)g * 64 + t], s);
        else             Svpart[((size_t)g * NSLICE + slice) * 64 + t] = s;
    }
    if (lane < 16) {
#pragma unroll
        for (int u = 0; u < 4; u++) {
            int m = wq * 64 + u * 16 + lane;
            if (NSLICE == 1) atomicAdd(&Aspart[(size_t)g * 256 + m], as_loc[u]);
            else             Aspart[((size_t)g * NSLICE + slice) * 256 + m] = as_loc[u];
        }
    }
    if (NSLICE == 1) {
        float* Ad = Apart + (size_t)g * (256 * 64);
#pragma unroll
        for (int u = 0; u < 4; u++)
#pragma unroll
        for (int u2 = 0; u2 < 4; u2++)
#pragma unroll
        for (int r = 0; r < 4; r++)
            atomicAdd(&Ad[(wq * 64 + u * 16 + lg * 4 + r) * 64 + u2 * 16 + li], cacc[u][u2][r]);
    } else {
        float* Ad = Apart + ((size_t)g * NSLICE + slice) * (256 * 64);
#pragma unroll
        for (int u = 0; u < 4; u++)
#pragma unroll
        for (int u2 = 0; u2 < 4; u2++)
#pragma unroll
        for (int r = 0; r < 4; r++)
            Ad[(wq * 64 + u * 16 + lg * 4 + r) * 64 + u2 * 16 + li] = cacc[u][u2][r];
    }
}

// ================= Kernel B: reduce partials (parallel) =================
__global__ __launch_bounds__(256)
void kernB(const float* __restrict__ Apart, const float* __restrict__ Aspart,
           const float* __restrict__ Svpart, const unsigned* __restrict__ mxk,
           float* __restrict__ ctx, float* __restrict__ ksum, int nslice)
{
    const int b = blockIdx.x;   // 0..15
    const int g = blockIdx.y;
    const int t = threadIdx.x;
    __shared__ float svh[64];
    float emx = __expf(-dec_f(mxk[g]));
    if (t < 64) {
        float s = 0.f;
        for (int sb = 0; sb < nslice; sb++) s += Svpart[((size_t)g * nslice + sb) * 64 + t];
        svh[t] = s;
    }
    if (b == 0) {
        float as_s = 0.f;
        for (int sb = 0; sb < nslice; sb++) as_s += Aspart[((size_t)g * nslice + sb) * 256 + t];
        ksum[(size_t)g * 256 + t] = emx * as_s + EPSC * (float)NSEQ;
    }
    __syncthreads();
    int idx4 = b * 256 + t;           // float4 index within head's 16384
    const f32x4* Ap = (const f32x4*)Apart;
    f32x4 s = zero4();
    for (int sb = 0; sb < nslice; sb++) s += Ap[((size_t)g * nslice + sb) * 4096 + idx4];
    int e0 = (idx4 * 4) & 63;
    f32x4 o;
    o[0] = emx * s[0] + EPSC * svh[e0];
    o[1] = emx * s[1] + EPSC * svh[e0 + 1];
    o[2] = emx * s[2] + EPSC * svh[e0 + 2];
    o[3] = emx * s[3] + EPSC * svh[e0 + 3];
    ((f32x4*)ctx)[(size_t)g * 4096 + idx4] = o;
}

// ================= Kernel C: Q-side + output =================
__global__ __launch_bounds__(256, 2)
void kernC(const float* __restrict__ qq, const float* __restrict__ proj,
           const float* __restrict__ ctx, const float* __restrict__ ksum,
           float* __restrict__ outp)
{
    const int slice = blockIdx.x;   // 0..15
    const int g     = blockIdx.y;
    const int t     = threadIdx.x;
    const int lane  = t & 63;
    const int wq    = t >> 6;
    const int li    = lane & 15;
    const int lg    = lane >> 4;

    __shared__ __align__(16) unsigned short Qhi[2048];
    __shared__ __align__(16) unsigned short Qlo[2048];
    __shared__ uint4 wbuf[4][544];   // per-wave union: qp hi/lo planes OR f32 out [32][68]
    __shared__ float diag[32];
    __shared__ float rmax4[4][32];
    __shared__ float comb[32];
    __shared__ float denp[4][32];
    __shared__ float denc[32];

    bf16x8 pfh[4][2], pfl[4][2];
#pragma unroll
    for (int u = 0; u < 4; u++)
#pragma unroll
    for (int s = 0; s < 2; s++) {
        const float* pr = proj + (size_t)(wq * 64 + u * 16 + li) * DDIM + s * 32 + lg * 8;
        u16x8 hh, ll;
#pragma unroll
        for (int j = 0; j < 8; j++) {
            unsigned short h, l;
            split_hl(NORMC * pr[j], h, l);
            hh[j] = h; ll[j] = l;
        }
        pfh[u][s] = __builtin_bit_cast(bf16x8, hh);
        pfl[u][s] = __builtin_bit_cast(bf16x8, ll);
    }
    bf16x8 cfh[4][2], cfl[4][2];
#pragma unroll
    for (int u2 = 0; u2 < 4; u2++)
#pragma unroll
    for (int s = 0; s < 2; s++) {
        u16x8 hh, ll;
#pragma unroll
        for (int j = 0; j < 8; j++) {
            unsigned short h, l;
            split_hl(ctx[((size_t)g * 256 + wq * 64 + s * 32 + lg * 8 + j) * 64 + u2 * 16 + li], h, l);
            hh[j] = h; ll[j] = l;
        }
        cfh[u2][s] = __builtin_bit_cast(bf16x8, hh);
        cfl[u2][s] = __builtin_bit_cast(bf16x8, ll);
    }
    float ksm[4];
#pragma unroll
    for (int u = 0; u < 4; u++) ksm[u] = ksum[(size_t)g * 256 + wq * 64 + u * 16 + li];

    unsigned short* qh = (unsigned short*)&wbuf[wq][0];
    unsigned short* ql = qh + 2048;
    float* ob = (float*)&wbuf[wq][0];

    const int stg_n = t >> 3;
    const int stg_c = t & 7;
    const int r_begin = slice * (NSEQ / 16);

    for (int r0 = r_begin; r0 < r_begin + NSEQ / 16; r0 += 32) {
        { // stage Q hi/lo planes + diag
            const float4* qb = (const float4*)(qq + ((size_t)g * NSEQ + r0 + stg_n) * DDIM + stg_c * 8);
            float4 a0 = qb[0], a1 = qb[1];
            float sq = a0.x*a0.x + a0.y*a0.y + a0.z*a0.z + a0.w*a0.w
                     + a1.x*a1.x + a1.y*a1.y + a1.z*a1.z + a1.w*a1.w;
            sq += __shfl_xor(sq, 1); sq += __shfl_xor(sq, 2); sq += __shfl_xor(sq, 4);
            if (stg_c == 0) diag[stg_n] = 0.0625f * sq;
            u16x8 h8, l8;
            {
                unsigned short h, l;
                split_hl(a0.x,h,l); h8[0]=h; l8[0]=l;
                split_hl(a0.y,h,l); h8[1]=h; l8[1]=l;
                split_hl(a0.z,h,l); h8[2]=h; l8[2]=l;
                split_hl(a0.w,h,l); h8[3]=h; l8[3]=l;
                split_hl(a1.x,h,l); h8[4]=h; l8[4]=l;
                split_hl(a1.y,h,l); h8[5]=h; l8[5]=l;
                split_hl(a1.z,h,l); h8[6]=h; l8[6]=l;
                split_hl(a1.w,h,l); h8[7]=h; l8[7]=l;
            }
            int idx = stg_n * 64 + (stg_c ^ (stg_n & 7)) * 8;
            *(u16x8*)&Qhi[idx] = h8;
            *(u16x8*)&Qlo[idx] = l8;
        }
        __syncthreads();
        // GEMM1: dash_q
        f32x4 dacc[2][4];
#pragma unroll
        for (int tt = 0; tt < 2; tt++)
#pragma unroll
        for (int u = 0; u < 4; u++) dacc[tt][u] = zero4();
#pragma unroll
        for (int tt = 0; tt < 2; tt++)
#pragma unroll
        for (int s = 0; s < 2; s++) {
            int idx = (tt * 16 + li) * 64 + ((s * 4 + lg) ^ (li & 7)) * 8;
            bf16x8 ah = ldfrag(&Qhi[idx]);
            bf16x8 al = ldfrag(&Qlo[idx]);
#pragma unroll
            for (int u = 0; u < 4; u++) dacc[tt][u] = mfma3(ah, al, pfh[u][s], pfl[u][s], dacc[tt][u]);
        }
        // row max over m
#pragma unroll
        for (int tt = 0; tt < 2; tt++)
#pragma unroll
        for (int r = 0; r < 4; r++) {
            float v = fmaxf(fmaxf(dacc[tt][0][r], dacc[tt][1][r]),
                            fmaxf(dacc[tt][2][r], dacc[tt][3][r]));
            v = fmaxf(v, __shfl_xor(v, 1));
            v = fmaxf(v, __shfl_xor(v, 2));
            v = fmaxf(v, __shfl_xor(v, 4));
            v = fmaxf(v, __shfl_xor(v, 8));
            if (li == 0) rmax4[wq][tt * 16 + lg * 4 + r] = v;
        }
        __syncthreads();
        if (t < 32) comb[t] = diag[t] + fmaxf(fmaxf(rmax4[0][t], rmax4[1][t]),
                                              fmaxf(rmax4[2][t], rmax4[3][t]));
        __syncthreads();
        // qp -> hi/lo planes (swizzled), den partials
        float dl[2][4] = {{0.f,0.f,0.f,0.f},{0.f,0.f,0.f,0.f}};
#pragma unroll
        for (int tt = 0; tt < 2; tt++) {
            float cb[4];
#pragma unroll
            for (int r = 0; r < 4; r++) cb[r] = comb[tt * 16 + lg * 4 + r];
#pragma unroll
            for (int u = 0; u < 4; u++)
#pragma unroll
            for (int r = 0; r < 4; r++) {
                float qp = __expf(dacc[tt][u][r] - cb[r]) + EPSC;
                dl[tt][r] += qp * ksm[u];
                int n = tt * 16 + lg * 4 + r;
                int m = u * 16 + li;
                int idx = n * 64 + (((m >> 3) ^ (n & 7)) << 3) + (m & 7);
                unsigned short h, l;
                split_hl(qp, h, l);
                qh[idx] = h;
                ql[idx] = l;
            }
        }
#pragma unroll
        for (int tt = 0; tt < 2; tt++)
#pragma unroll
        for (int r = 0; r < 4; r++) {
            float v = dl[tt][r];
            v += __shfl_xor(v, 1); v += __shfl_xor(v, 2);
            v += __shfl_xor(v, 4); v += __shfl_xor(v, 8);
            if (li == 0) denp[wq][tt * 16 + lg * 4 + r] = v;
        }
        __syncthreads();
        if (t < 32) denc[t] = denp[0][t] + denp[1][t] + denp[2][t] + denp[3][t];
        // GEMM3: out-partial
        f32x4 oacc[2][4];
#pragma unroll
        for (int tt = 0; tt < 2; tt++)
#pragma unroll
        for (int u2 = 0; u2 < 4; u2++) oacc[tt][u2] = zero4();
#pragma unroll
        for (int s = 0; s < 2; s++)
#pragma unroll
        for (int tt = 0; tt < 2; tt++) {
            int n = tt * 16 + li;
            int idx = n * 64 + ((s * 4 + lg) ^ (n & 7)) * 8;
            bf16x8 ah = ldfrag(&qh[idx]);
            bf16x8 al = ldfrag(&ql[idx]);
#pragma unroll
            for (int u2 = 0; u2 < 4; u2++)
                oacc[tt][u2] = mfma3(ah, al, cfh[u2][s], cfl[u2][s], oacc[tt][u2]);
        }
        // write out partials (reuse wave buffer as f32 [32][68])
#pragma unroll
        for (int tt = 0; tt < 2; tt++)
#pragma unroll
        for (int u2 = 0; u2 < 4; u2++)
#pragma unroll
        for (int r = 0; r < 4; r++)
            ob[(tt * 16 + lg * 4 + r) * 68 + u2 * 16 + li] = oacc[tt][u2][r];
        __syncthreads();
        { // combine 4 wave partials, divide, write out
            float dinv = 1.0f / denc[stg_n];
            float o[8];
#pragma unroll
            for (int j = 0; j < 8; j++) {
                float s = 0.f;
#pragma unroll
                for (int w4 = 0; w4 < 4; w4++)
                    s += ((const float*)&wbuf[w4][0])[stg_n * 68 + stg_c * 8 + j];
                o[j] = s * dinv;
            }
            float4 o0 = {o[0], o[1], o[2], o[3]};
            float4 o1 = {o[4], o[5], o[6], o[7]};
            float* op = outp + ((size_t)g * NSEQ + r0 + stg_n) * DDIM + stg_c * 8;
            ((float4*)op)[0] = o0;
            ((float4*)op)[1] = o1;
        }
        __syncthreads();
    }
}

extern "C" void kernel_launch(void* const* d_in, const int* in_sizes, int n_in,
                              void* d_out, int out_size, void* d_ws, size_t ws_size,
                              hipStream_t stream)
{
    const float* q    = (const float*)d_in[0];
    const float* k    = (const float*)d_in[1];
    const float* v    = (const float*)d_in[2];
    const float* proj = (const float*)d_in[3];
    float* outp = (float*)d_out;

    size_t per_ns = (size_t)GH * 16384 + (size_t)GH * 256 + (size_t)GH * 64; // floats per slice-set
    size_t fixed  = (size_t)GH * 16384 + (size_t)GH * 256;                   // ctx + ksum floats
    size_t need16 = 256 + 4 * (16 * per_ns + fixed);
    size_t need8  = 256 + 4 * (8 * per_ns + fixed);
    int ns = (ws_size >= need16) ? 16 : ((ws_size >= need8) ? 8 : 1);

    unsigned* mxk = (unsigned*)d_ws;
    float* Apart  = (float*)((char*)d_ws + 256);
    float* Aspart = Apart  + (size_t)GH * ns * 16384;
    float* Svpart = Aspart + (size_t)GH * ns * 256;
    float* ctx    = Svpart + (size_t)GH * ns * 64;
    float* ksum   = ctx    + (size_t)GH * 16384;

    if (ns == 16) {
        hipMemsetAsync(d_ws, 0, 256, stream);
        kernA<16><<<dim3(16, GH), 256, 0, stream>>>(k, v, proj, Apart, Aspart, Svpart, mxk);
    } else if (ns == 8) {
        hipMemsetAsync(d_ws, 0, 256, stream);
        kernA<8><<<dim3(8, GH), 256, 0, stream>>>(k, v, proj, Apart, Aspart, Svpart, mxk);
    } else {
        hipMemsetAsync(d_ws, 0, 256 + 4 * per_ns, stream);
        kernA<1><<<dim3(8, GH), 256, 0, stream>>>(k, v, proj, Apart, Aspart, Svpart, mxk);
    }
    kernB<<<dim3(16, GH), 256, 0, stream>>>(Apart, Aspart, Svpart, mxk, ctx, ksum, ns);
    kernC<<<dim3(16, GH), 256, 0, stream>>>(q, proj, ctx, ksum, outp);
}